// Round 5
// baseline (373.025 us; speedup 1.0000x reference)
//
#include <hip/hip_runtime.h>

#define NTOK  16384   // B*T
#define KDIM  512
#define NQKV  1536
#define TT    4096

using frag8   = __attribute__((ext_vector_type(8))) short;
using floatx4 = __attribute__((ext_vector_type(4))) float;

__device__ __forceinline__ unsigned short f2b(float f) {
  union { float f; unsigned u; } v; v.f = f;
  unsigned r = v.u + 0x7fffu + ((v.u >> 16) & 1u);
  return (unsigned short)(r >> 16);
}
__device__ __forceinline__ float b2f(unsigned short s) {
  union { unsigned u; float f; } v; v.u = ((unsigned)s) << 16; return v.f;
}
__device__ __forceinline__ float blo(unsigned w) {
  union { unsigned u; float f; } v; v.u = w << 16; return v.f;
}
__device__ __forceinline__ float bhi(unsigned w) {
  union { unsigned u; float f; } v; v.u = w & 0xffff0000u; return v.f;
}

__device__ __forceinline__ void gl_lds16(const void* g, void* l) {
  __builtin_amdgcn_global_load_lds((__attribute__((address_space(1))) const void*)g,
                                   (__attribute__((address_space(3))) void*)l,
                                   16, 0, 0);
}

// ---------------- fused convert: x -> bf16, weights -> bf16 (float4), bias concat --------
__global__ __launch_bounds__(256) void cvt_all(
    const float* __restrict__ x,
    const float* __restrict__ Wq, const float* __restrict__ Wk,
    const float* __restrict__ Wv, const float* __restrict__ Wp,
    const float* __restrict__ bq, const float* __restrict__ bk,
    const float* __restrict__ bv,
    unsigned short* __restrict__ xb,
    unsigned short* __restrict__ wqkv, unsigned short* __restrict__ wp,
    float* __restrict__ bias_qkv) {
  const int blk = blockIdx.x;
  if (blk < 8192) {                          // x: 8.4M floats, float4 per thread
    const size_t i = (size_t)blk * 256 + threadIdx.x;
    const float4 v = ((const float4*)x)[i];
    ushort4 o;
    o.x = f2b(v.x); o.y = f2b(v.y); o.z = f2b(v.z); o.w = f2b(v.w);
    ((ushort4*)xb)[i] = o;
    return;
  }
  int idx = (blk - 8192) * 256 + threadIdx.x;
  if (idx < 196608) {                       // wqkv: 1536 rows x 128 float4
    const int m = idx >> 7, c4 = (idx & 127) << 2;
    const float* W = (m < 512) ? Wq : ((m < 1024) ? Wk : Wv);
    const float4 v = *(const float4*)&W[(m & 511) * 512 + c4];
    ushort4 o;
    o.x = f2b(v.x); o.y = f2b(v.y); o.z = f2b(v.z); o.w = f2b(v.w);
    *(ushort4*)&wqkv[m * 512 + c4] = o;
    return;
  }
  idx -= 196608;
  if (idx < 65536) {                        // wp: 65536 float4
    const float4 v = ((const float4*)Wp)[idx];
    ushort4 o;
    o.x = f2b(v.x); o.y = f2b(v.y); o.z = f2b(v.z); o.w = f2b(v.w);
    ((ushort4*)wp)[idx] = o;
    return;
  }
  idx -= 65536;
  if (idx < 1536)
    bias_qkv[idx] = (idx < 512) ? bq[idx]
                  : ((idx < 1024) ? bk[idx - 512] : bv[idx - 1024]);
}

// ---------------- bf16 GEMM, B^T input, XCD-swizzled, BK=64 + XOR LDS swizzle ----------------
// Verified round-0 structure (128x128 tile, 4 waves, single-buffered staging,
// __syncthreads). SOFT=1: fused per-head softmax on q/k regions, coalesced bf16
// store via padded LDS repack. SOFT=0: fp32 store + bias, coalesced float4 repack.
template<int SOFT>
__global__ __launch_bounds__(256, 2) void gemm_bt(
    const unsigned short* __restrict__ A,
    const unsigned short* __restrict__ Bm,
    const float* __restrict__ bias,
    void* __restrict__ C,
    int M, int N, int K, int ldc)
{
  // staging needs 16384 shorts; bf16 repack needs 64*132=8448; fp32 repack needs
  // 64*130 floats = 16640 shorts. 16640 shorts = 33280 B -> still 4 blocks/CU by LDS.
  __shared__ unsigned short sh[16640];
  unsigned short* As = sh;
  unsigned short* Bs = sh + 128 * 64;
  const int tid  = threadIdx.x;
  const int wave = tid >> 6;
  const int lane = tid & 63;
  const int quad = lane >> 4;
  const int lr   = lane & 15;
  const int sw7  = lr & 7;
  // XCD swizzle: keep all n-tiles of an m-tile on one XCD (L2 A-reuse)
  const int bid  = ((blockIdx.x & 7) * (gridDim.x >> 3)) + (blockIdx.x >> 3);
  const int nt   = N >> 7;
  const int bn   = (bid % nt) << 7;
  const int bm   = (bid / nt) << 7;
  const int half = wave >> 1;
  const int wm   = half << 6;
  const int wn   = (wave & 1) << 6;

  floatx4 acc[4][4] = {};

  // staging: thread t -> row = t/8 (+32/round), global 16B chunk = (t&7) ^ (row&7)
  // gl_lds16 writes lane l -> ldsbase + 16*l, so LDS chunk (t&7) of row holds
  // global chunk (t&7)^(row&7): XOR swizzle kills the 128B-row bank alias.
  const int srow = tid >> 3;
  const int scol = ((tid & 7) ^ ((tid >> 3) & 7)) << 3;
  const unsigned short* Ag = A + (size_t)(bm + srow) * K + scol;
  const unsigned short* Bg = Bm + (size_t)(bn + srow) * K + scol;
  unsigned short* Al = As + (wave << 9);   // wave*512 shorts = 1 KB
  unsigned short* Bl = Bs + (wave << 9);

  for (int k0 = 0; k0 < K; k0 += 64) {
    __syncthreads();
    gl_lds16(Ag + k0,                    Al);
    gl_lds16(Ag + (size_t)32 * K + k0,   Al + 2048);
    gl_lds16(Ag + (size_t)64 * K + k0,   Al + 4096);
    gl_lds16(Ag + (size_t)96 * K + k0,   Al + 6144);
    gl_lds16(Bg + k0,                    Bl);
    gl_lds16(Bg + (size_t)32 * K + k0,   Bl + 2048);
    gl_lds16(Bg + (size_t)64 * K + k0,   Bl + 4096);
    gl_lds16(Bg + (size_t)96 * K + k0,   Bl + 6144);
    __syncthreads();

#pragma unroll
    for (int kk = 0; kk < 2; kk++) {
      const int coff = ((((kk << 2) + quad) ^ sw7) << 3);
      frag8 af[4], bf[4];
#pragma unroll
      for (int i = 0; i < 4; i++)
        af[i] = *(const frag8*)&As[(wm + (i << 4) + lr) * 64 + coff];
#pragma unroll
      for (int j = 0; j < 4; j++)
        bf[j] = *(const frag8*)&Bs[(wn + (j << 4) + lr) * 64 + coff];
#pragma unroll
      for (int i = 0; i < 4; i++)
#pragma unroll
        for (int j = 0; j < 4; j++)
          acc[i][j] = __builtin_amdgcn_mfma_f32_16x16x32_bf16(af[i], bf[j], acc[i][j], 0, 0, 0);
    }
  }

  // epilogue: C/D layout col=lane&15, row=quad*4+reg
  const int ccol0 = bn + wn + lr;

#pragma unroll
  for (int j = 0; j < 4; j++) {
    const float bv = bias[ccol0 + (j << 4)];
#pragma unroll
    for (int i = 0; i < 4; i++)
#pragma unroll
      for (int r = 0; r < 4; r++)
        acc[i][j][r] += bv;
  }

  if (SOFT) {
    const int region = (bn + wn) >> 9;   // 0=q, 1=k, 2=v (wave-uniform)
    if (region < 2) {
#pragma unroll
      for (int i = 0; i < 4; i++)
#pragma unroll
        for (int r = 0; r < 4; r++) {
          float e0 = __expf(acc[i][0][r]);
          float e1 = __expf(acc[i][1][r]);
          float e2 = __expf(acc[i][2][r]);
          float e3 = __expf(acc[i][3][r]);
          float s = e0 + e1 + e2 + e3;
          s += __shfl_xor(s, 1);
          s += __shfl_xor(s, 2);
          s += __shfl_xor(s, 4);
          s += __shfl_xor(s, 8);
          const float inv = 1.f / s;
          acc[i][0][r] = e0 * inv; acc[i][1][r] = e1 * inv;
          acc[i][2][r] = e2 * inv; acc[i][3][r] = e3 * inv;
        }
    }
    // coalesced bf16 store via padded LDS repack (stride 132: quads 8 banks apart, 2-way max)
    unsigned short* os = sh;
#pragma unroll
    for (int p = 0; p < 2; p++) {
      __syncthreads();
      if (half == p) {
#pragma unroll
        for (int i = 0; i < 4; i++)
#pragma unroll
          for (int j = 0; j < 4; j++)
#pragma unroll
            for (int r = 0; r < 4; r++)
              os[((i << 4) + (quad << 2) + r) * 132 + wn + (j << 4) + lr] = f2b(acc[i][j][r]);
      }
      __syncthreads();
#pragma unroll
      for (int it = 0; it < 4; it++) {
        const int idx = (it << 8) + tid;   // 1024 uint4 total
        const int row = idx >> 4;
        const int c8  = (idx & 15) << 3;
        *(uint4*)((unsigned short*)C + (size_t)(bm + (p << 6) + row) * ldc + bn + c8) =
            *(const uint4*)&os[row * 132 + c8];
      }
    }
  } else {
    // coalesced fp32 store via padded LDS repack (stride 130 floats: conflict-free)
    float* osf = (float*)sh;
#pragma unroll
    for (int p = 0; p < 2; p++) {
      __syncthreads();
      if (half == p) {
#pragma unroll
        for (int i = 0; i < 4; i++)
#pragma unroll
          for (int j = 0; j < 4; j++)
#pragma unroll
            for (int r = 0; r < 4; r++)
              osf[((i << 4) + (quad << 2) + r) * 130 + wn + (j << 4) + lr] = acc[i][j][r];
      }
      __syncthreads();
#pragma unroll
      for (int it = 0; it < 8; it++) {
        const int idx = (it << 8) + tid;   // 2048 float4 total
        const int row = idx >> 5;
        const int c4  = (idx & 31) << 2;
        *(float4*)((float*)C + (size_t)(bm + (p << 6) + row) * ldc + bn + c4) =
            *(const float4*)&osf[row * 130 + c4];
      }
    }
  }
}

// ---------------- partial ctxT[e][d] + ksum partial per (chunk,bh) ----------------
// Wave-local rewrite: each wave owns a disjoint 128-token range and stages its own
// K/V slabs into private LDS via global_load_lds. Producer == consumer wave, so
// ordering needs only in-order s_waitcnt (NO s_barrier / __syncthreads anywhere:
// race-free by construction). 8e x 8d register blocking: 2 ds_read_b128 per 64
// FMA (4x better LDS-pipe ratio than the 4x4 version). Slabs double-buffered
// with wave-private counted vmcnt(4).
// part/ksp layouts identical to previous version (32 chunks per bh).
__global__ __launch_bounds__(128) void kv_context(const unsigned short* __restrict__ qkv,
                                                  float* __restrict__ part,
                                                  float* __restrict__ ksp) {
  const int bid = blockIdx.x;          // bh(32) x tc(16), tc-fast
  const int tc  = bid & 15;
  const int bh  = bid >> 4;
  const int b   = bh >> 3, h = bh & 7;
  __shared__ __align__(16) unsigned short kvl[8192];  // per wave 4096: 2 bufs x (ks 1024 | vs 1024)
  const int tid  = threadIdx.x;
  const int w    = tid >> 6;         // 2 waves
  const int lane = tid & 63;
  const int ey   = lane >> 3;        // 0..7  e-group (8 e's each)
  const int dx   = lane & 7;         // 0..7  d-group (8 d's each)
  const int t0   = b * TT + tc * 256 + w * 128;
  const int chunk = tc * 2 + w;      // 0..31 per bh

  unsigned short* const L = kvl + (w << 12);   // wave-private 4096 shorts

  // per-lane global sources: lane l covers token (l>>3), 16B chunk (l&7) -> LDS
  // linear dest base + 16*l lands exactly at [row l>>3][chunk l&7] of a [8][64] slab.
  const unsigned short* kg = qkv + (size_t)(t0 + ey) * NQKV + 512 + h * 64 + (dx << 3);
  const unsigned short* vg = kg + 512;

  auto ISSUE = [&](int s) {            // stage slab s (16 tokens) into buf s&1
    unsigned short* B = L + ((s & 1) << 11);      // 2048 shorts per buf
    const size_t roff = (size_t)(s << 4) * NQKV;  // s*16 tokens
    gl_lds16(kg + roff,                    B);
    gl_lds16(kg + roff + (size_t)8 * NQKV, B + 512);
    gl_lds16(vg + roff,                    B + 1024);
    gl_lds16(vg + roff + (size_t)8 * NQKV, B + 1536);
  };

  float acc[8][8] = {};
  float ksacc[8] = {};

  ISSUE(0); ISSUE(1);
#pragma unroll
  for (int s = 0; s < 8; ++s) {
    if (s < 7) { asm volatile("s_waitcnt vmcnt(4)" ::: "memory"); }   // slab s landed
    else       { asm volatile("s_waitcnt vmcnt(0)" ::: "memory"); }
    __builtin_amdgcn_sched_barrier(0);
    const unsigned short* ks = L + ((s & 1) << 11);
    const unsigned short* vs = ks + 1024;
#pragma unroll
    for (int t = 0; t < 16; ++t) {
      const uint4 kr = *(const uint4*)&ks[t * 64 + (dx << 3)];  // 8 d's (broadcast x8)
      const uint4 vr = *(const uint4*)&vs[t * 64 + (ey << 3)];  // 8 e's (broadcast x8)
      float kf[8] = {blo(kr.x), bhi(kr.x), blo(kr.y), bhi(kr.y),
                     blo(kr.z), bhi(kr.z), blo(kr.w), bhi(kr.w)};
      float vf[8] = {blo(vr.x), bhi(vr.x), blo(vr.y), bhi(vr.y),
                     blo(vr.z), bhi(vr.z), blo(vr.w), bhi(vr.w)};
#pragma unroll
      for (int i = 0; i < 8; ++i) ksacc[i] += kf[i];
#pragma unroll
      for (int e = 0; e < 8; ++e)
#pragma unroll
        for (int d = 0; d < 8; ++d)
          acc[e][d] += vf[e] * kf[d];
    }
    if (s + 2 < 8) {
      // all ds_reads of buf s&1 retired (lgkmcnt==0) before overwriting it
      asm volatile("s_waitcnt lgkmcnt(0)" ::: "memory");
      __builtin_amdgcn_sched_barrier(0);
      ISSUE(s + 2);
    }
  }

  float* pg = part + ((size_t)(chunk * 32 + bh) << 12) + (size_t)(ey << 3) * 64 + (dx << 3);
#pragma unroll
  for (int e = 0; e < 8; ++e) {
    floatx4 lo = {acc[e][0], acc[e][1], acc[e][2], acc[e][3]};
    floatx4 hi = {acc[e][4], acc[e][5], acc[e][6], acc[e][7]};
    *(floatx4*)(pg + e * 64)     = lo;
    *(floatx4*)(pg + e * 64 + 4) = hi;
  }
  if (ey == 0) {
#pragma unroll
    for (int i = 0; i < 8; ++i)
      ksp[(chunk * 32 + bh) * 64 + (dx << 3) + i] = ksacc[i];
  }
}

// ---------------- reduce partials -> ctxb bf16 [bh][80][64] ----------------
// rows 0-63 = ctxT, row 64 = ksum, rows 65-79 = 0
__global__ __launch_bounds__(256) void ctx_reduce(const float* __restrict__ part,
                                                  const float* __restrict__ ksp,
                                                  unsigned short* __restrict__ ctxb) {
  const int bh = blockIdx.x / 5, g = blockIdx.x % 5;
  const int row = (g << 4) + (threadIdx.x >> 4);
  const int d0  = (threadIdx.x & 15) << 2;
  floatx4 s = {0.f, 0.f, 0.f, 0.f};
  if (row < 64) {
    const float* p = part + ((size_t)bh << 12) + row * 64 + d0;
    for (int c = 0; c < 32; c++)
      s += *(const floatx4*)(p + ((size_t)c << 17));
  } else if (row == 64) {
    const float* p = ksp + bh * 64 + d0;
    for (int c = 0; c < 32; c++)
      s += *(const floatx4*)(p + (c << 11));
  }
  ushort4 o;
  o.x = f2b(s.x); o.y = f2b(s.y); o.z = f2b(s.z); o.w = f2b(s.w);
  *(ushort4*)&ctxb[(size_t)bh * 5120 + (row << 6) + d0] = o;
}

// ---------------- attn_out via MFMA: outT[e][t] = ctxT[e][:]·q'[t][:] ----------------
__global__ __launch_bounds__(256) void attn_out(const unsigned short* __restrict__ qkv,
                                                const unsigned short* __restrict__ ctxb,
                                                unsigned short* __restrict__ opre) {
  const int tc = blockIdx.x >> 5;      // bh-fast
  const int bh = blockIdx.x & 31;
  const int b = bh >> 3, h = bh & 7;
  const int t0 = b * TT + (tc << 6);
  __shared__ unsigned short sh[144 * 72];   // qs[64][72] | cs[80][72] (cs reused as os)
  unsigned short* qs = sh;
  unsigned short* cs = sh + 64 * 72;
  unsigned short* os = cs;
  const int tid = threadIdx.x;

  for (int i = tid; i < 512; i += 256) {
    const int row = i >> 3, c8 = (i & 7) << 3;
    *(uint4*)&qs[row * 72 + c8] =
        *(const uint4*)&qkv[(size_t)(t0 + row) * NQKV + h * 64 + c8];
  }
  for (int i = tid; i < 640; i += 256) {
    const int row = i >> 3, c8 = (i & 7) << 3;
    *(uint4*)&cs[row * 72 + c8] =
        *(const uint4*)&ctxb[(size_t)bh * 5120 + (row << 6) + c8];
  }
  __syncthreads();

  const int lane = tid & 63, w = tid >> 6, quad = lane >> 4, lr = lane & 15;
  floatx4 acc[5] = {};
#pragma unroll
  for (int k2 = 0; k2 < 2; k2++) {
    const int d0 = (k2 << 5) + (quad << 3);
    const frag8 bf = *(const frag8*)&qs[((w << 4) + lr) * 72 + d0];
#pragma unroll
    for (int et = 0; et < 5; et++) {
      const frag8 af = *(const frag8*)&cs[(et * 16 + lr) * 72 + d0];
      acc[et] = __builtin_amdgcn_mfma_f32_16x16x32_bf16(af, bf, acc[et], 0, 0, 0);
    }
  }
  const float dinv = 1.f / __shfl(acc[4][0], lr);
  __syncthreads();                      // done reading cs; reuse as os

  const int trow = (w << 4) + lr;
#pragma unroll
  for (int et = 0; et < 4; et++)
#pragma unroll
    for (int r = 0; r < 4; r++) {
      const int e = et * 16 + (quad << 2) + r;
      const float qv = b2f(qs[trow * 72 + e]);
      os[trow * 72 + e] = f2b(acc[et][r] * dinv + qv);
    }
  __syncthreads();

  for (int i = tid; i < 512; i += 256) {
    const int row = i >> 3, c8 = (i & 7) << 3;
    *(uint4*)&opre[(size_t)(t0 + row) * KDIM + h * 64 + c8] = *(const uint4*)&os[row * 72 + c8];
  }
}

// ---------------- launch ----------------
extern "C" void kernel_launch(void* const* d_in, const int* in_sizes, int n_in,
                              void* d_out, int out_size, void* d_ws, size_t ws_size,
                              hipStream_t stream) {
  (void)in_sizes; (void)n_in; (void)out_size; (void)ws_size;
  const float* x  = (const float*)d_in[0];
  const float* Wq = (const float*)d_in[1];
  const float* bq = (const float*)d_in[2];
  const float* Wk = (const float*)d_in[3];
  const float* bk = (const float*)d_in[4];
  const float* Wv = (const float*)d_in[5];
  const float* bv = (const float*)d_in[6];
  const float* Wp = (const float*)d_in[7];
  const float* bp = (const float*)d_in[8];

  char* w = (char*)d_ws;
  unsigned short* xb   = (unsigned short*)w; w += (size_t)NTOK * KDIM * 2;   // 16 MB
  float* part          = (float*)xb;         // alias: xb dead after qkv GEMM
  unsigned short* wqkv = (unsigned short*)w; w += (size_t)NQKV * KDIM * 2;   // 1.5 MB
  unsigned short* wp   = (unsigned short*)w; w += (size_t)KDIM * KDIM * 2;   // 0.5 MB
  float* bias_qkv      = (float*)w;          w += (size_t)NQKV * 4;          // 6 KB
  float* ksp           = (float*)w;          w += (size_t)1024 * 64 * 4;     // 256 KB
  unsigned short* ctxb = (unsigned short*)w; w += (size_t)32 * 80 * 64 * 2;  // 320 KB
  unsigned short* qkv  = (unsigned short*)w; w += (size_t)NTOK * NQKV * 2;   // 48 MB
  unsigned short* opre = (unsigned short*)w; w += (size_t)NTOK * KDIM * 2;   // 16 MB

  cvt_all<<<9222, 256, 0, stream>>>(x, Wq, Wk, Wv, Wp, bq, bk, bv,
                                    xb, wqkv, wp, bias_qkv);
  gemm_bt<1><<<(NTOK / 128) * (NQKV / 128), 256, 0, stream>>>(
      xb, wqkv, bias_qkv, qkv, NTOK, NQKV, KDIM, NQKV);
  kv_context<<<512, 128, 0, stream>>>(qkv, part, ksp);
  ctx_reduce<<<160, 256, 0, stream>>>(part, ksp, ctxb);
  attn_out<<<2048, 256, 0, stream>>>(qkv, ctxb, opre);
  gemm_bt<0><<<(NTOK / 128) * (KDIM / 128), 256, 0, stream>>>(
      opre, wp, bp, d_out, NTOK, KDIM, KDIM, KDIM);
}

// Round 6
// 177.192 us; speedup vs baseline: 2.1052x; 2.1052x over previous
//
#include <hip/hip_runtime.h>

#define NTOK  16384   // B*T
#define KDIM  512
#define NQKV  1536
#define TT    4096

using frag8   = __attribute__((ext_vector_type(8))) short;
using floatx4 = __attribute__((ext_vector_type(4))) float;

__device__ __forceinline__ unsigned short f2b(float f) {
  union { float f; unsigned u; } v; v.f = f;
  unsigned r = v.u + 0x7fffu + ((v.u >> 16) & 1u);
  return (unsigned short)(r >> 16);
}
__device__ __forceinline__ float b2f(unsigned short s) {
  union { unsigned u; float f; } v; v.u = ((unsigned)s) << 16; return v.f;
}
__device__ __forceinline__ float blo(unsigned w) {
  union { unsigned u; float f; } v; v.u = w << 16; return v.f;
}
__device__ __forceinline__ float bhi(unsigned w) {
  union { unsigned u; float f; } v; v.u = w & 0xffff0000u; return v.f;
}

__device__ __forceinline__ void gl_lds16(const void* g, void* l) {
  __builtin_amdgcn_global_load_lds((__attribute__((address_space(1))) const void*)g,
                                   (__attribute__((address_space(3))) void*)l,
                                   16, 0, 0);
}

// ---------------- fused convert: x -> bf16, weights -> bf16 (float4), bias concat --------
__global__ __launch_bounds__(256) void cvt_all(
    const float* __restrict__ x,
    const float* __restrict__ Wq, const float* __restrict__ Wk,
    const float* __restrict__ Wv, const float* __restrict__ Wp,
    const float* __restrict__ bq, const float* __restrict__ bk,
    const float* __restrict__ bv,
    unsigned short* __restrict__ xb,
    unsigned short* __restrict__ wqkv, unsigned short* __restrict__ wp,
    float* __restrict__ bias_qkv) {
  const int blk = blockIdx.x;
  if (blk < 8192) {                          // x: 8.4M floats, float4 per thread
    const size_t i = (size_t)blk * 256 + threadIdx.x;
    const float4 v = ((const float4*)x)[i];
    ushort4 o;
    o.x = f2b(v.x); o.y = f2b(v.y); o.z = f2b(v.z); o.w = f2b(v.w);
    ((ushort4*)xb)[i] = o;
    return;
  }
  int idx = (blk - 8192) * 256 + threadIdx.x;
  if (idx < 196608) {                       // wqkv: 1536 rows x 128 float4
    const int m = idx >> 7, c4 = (idx & 127) << 2;
    const float* W = (m < 512) ? Wq : ((m < 1024) ? Wk : Wv);
    const float4 v = *(const float4*)&W[(m & 511) * 512 + c4];
    ushort4 o;
    o.x = f2b(v.x); o.y = f2b(v.y); o.z = f2b(v.z); o.w = f2b(v.w);
    *(ushort4*)&wqkv[m * 512 + c4] = o;
    return;
  }
  idx -= 196608;
  if (idx < 65536) {                        // wp: 65536 float4
    const float4 v = ((const float4*)Wp)[idx];
    ushort4 o;
    o.x = f2b(v.x); o.y = f2b(v.y); o.z = f2b(v.z); o.w = f2b(v.w);
    ((ushort4*)wp)[idx] = o;
    return;
  }
  idx -= 65536;
  if (idx < 1536)
    bias_qkv[idx] = (idx < 512) ? bq[idx]
                  : ((idx < 1024) ? bk[idx - 512] : bv[idx - 1024]);
}

// ---------------- bf16 GEMM, B^T input, XCD-swizzled, BK=64 + XOR LDS swizzle ----------------
// Verified round-0 structure (128x128 tile, 4 waves, single-buffered staging,
// __syncthreads). SOFT=1: fused per-head softmax on q/k regions, coalesced bf16
// store via padded LDS repack. SOFT=0: fp32 store + bias, coalesced float4 repack.
template<int SOFT>
__global__ __launch_bounds__(256, 2) void gemm_bt(
    const unsigned short* __restrict__ A,
    const unsigned short* __restrict__ Bm,
    const float* __restrict__ bias,
    void* __restrict__ C,
    int M, int N, int K, int ldc)
{
  // staging needs 16384 shorts; bf16 repack needs 64*132=8448; fp32 repack needs
  // 64*130 floats = 16640 shorts. 16640 shorts = 33280 B -> still 4 blocks/CU by LDS.
  __shared__ unsigned short sh[16640];
  unsigned short* As = sh;
  unsigned short* Bs = sh + 128 * 64;
  const int tid  = threadIdx.x;
  const int wave = tid >> 6;
  const int lane = tid & 63;
  const int quad = lane >> 4;
  const int lr   = lane & 15;
  const int sw7  = lr & 7;
  // XCD swizzle: keep all n-tiles of an m-tile on one XCD (L2 A-reuse)
  const int bid  = ((blockIdx.x & 7) * (gridDim.x >> 3)) + (blockIdx.x >> 3);
  const int nt   = N >> 7;
  const int bn   = (bid % nt) << 7;
  const int bm   = (bid / nt) << 7;
  const int half = wave >> 1;
  const int wm   = half << 6;
  const int wn   = (wave & 1) << 6;

  floatx4 acc[4][4] = {};

  // staging: thread t -> row = t/8 (+32/round), global 16B chunk = (t&7) ^ (row&7)
  // gl_lds16 writes lane l -> ldsbase + 16*l, so LDS chunk (t&7) of row holds
  // global chunk (t&7)^(row&7): XOR swizzle kills the 128B-row bank alias.
  const int srow = tid >> 3;
  const int scol = ((tid & 7) ^ ((tid >> 3) & 7)) << 3;
  const unsigned short* Ag = A + (size_t)(bm + srow) * K + scol;
  const unsigned short* Bg = Bm + (size_t)(bn + srow) * K + scol;
  unsigned short* Al = As + (wave << 9);   // wave*512 shorts = 1 KB
  unsigned short* Bl = Bs + (wave << 9);

  for (int k0 = 0; k0 < K; k0 += 64) {
    __syncthreads();
    gl_lds16(Ag + k0,                    Al);
    gl_lds16(Ag + (size_t)32 * K + k0,   Al + 2048);
    gl_lds16(Ag + (size_t)64 * K + k0,   Al + 4096);
    gl_lds16(Ag + (size_t)96 * K + k0,   Al + 6144);
    gl_lds16(Bg + k0,                    Bl);
    gl_lds16(Bg + (size_t)32 * K + k0,   Bl + 2048);
    gl_lds16(Bg + (size_t)64 * K + k0,   Bl + 4096);
    gl_lds16(Bg + (size_t)96 * K + k0,   Bl + 6144);
    __syncthreads();

#pragma unroll
    for (int kk = 0; kk < 2; kk++) {
      const int coff = ((((kk << 2) + quad) ^ sw7) << 3);
      frag8 af[4], bf[4];
#pragma unroll
      for (int i = 0; i < 4; i++)
        af[i] = *(const frag8*)&As[(wm + (i << 4) + lr) * 64 + coff];
#pragma unroll
      for (int j = 0; j < 4; j++)
        bf[j] = *(const frag8*)&Bs[(wn + (j << 4) + lr) * 64 + coff];
#pragma unroll
      for (int i = 0; i < 4; i++)
#pragma unroll
        for (int j = 0; j < 4; j++)
          acc[i][j] = __builtin_amdgcn_mfma_f32_16x16x32_bf16(af[i], bf[j], acc[i][j], 0, 0, 0);
    }
  }

  // epilogue: C/D layout col=lane&15, row=quad*4+reg
  const int ccol0 = bn + wn + lr;

#pragma unroll
  for (int j = 0; j < 4; j++) {
    const float bv = bias[ccol0 + (j << 4)];
#pragma unroll
    for (int i = 0; i < 4; i++)
#pragma unroll
      for (int r = 0; r < 4; r++)
        acc[i][j][r] += bv;
  }

  if (SOFT) {
    const int region = (bn + wn) >> 9;   // 0=q, 1=k, 2=v (wave-uniform)
    if (region < 2) {
#pragma unroll
      for (int i = 0; i < 4; i++)
#pragma unroll
        for (int r = 0; r < 4; r++) {
          float e0 = __expf(acc[i][0][r]);
          float e1 = __expf(acc[i][1][r]);
          float e2 = __expf(acc[i][2][r]);
          float e3 = __expf(acc[i][3][r]);
          float s = e0 + e1 + e2 + e3;
          s += __shfl_xor(s, 1);
          s += __shfl_xor(s, 2);
          s += __shfl_xor(s, 4);
          s += __shfl_xor(s, 8);
          const float inv = 1.f / s;
          acc[i][0][r] = e0 * inv; acc[i][1][r] = e1 * inv;
          acc[i][2][r] = e2 * inv; acc[i][3][r] = e3 * inv;
        }
    }
    // coalesced bf16 store via padded LDS repack (stride 132: quads 8 banks apart, 2-way max)
    unsigned short* os = sh;
#pragma unroll
    for (int p = 0; p < 2; p++) {
      __syncthreads();
      if (half == p) {
#pragma unroll
        for (int i = 0; i < 4; i++)
#pragma unroll
          for (int j = 0; j < 4; j++)
#pragma unroll
            for (int r = 0; r < 4; r++)
              os[((i << 4) + (quad << 2) + r) * 132 + wn + (j << 4) + lr] = f2b(acc[i][j][r]);
      }
      __syncthreads();
#pragma unroll
      for (int it = 0; it < 4; it++) {
        const int idx = (it << 8) + tid;   // 1024 uint4 total
        const int row = idx >> 4;
        const int c8  = (idx & 15) << 3;
        *(uint4*)((unsigned short*)C + (size_t)(bm + (p << 6) + row) * ldc + bn + c8) =
            *(const uint4*)&os[row * 132 + c8];
      }
    }
  } else {
    // coalesced fp32 store via padded LDS repack (stride 130 floats: conflict-free)
    float* osf = (float*)sh;
#pragma unroll
    for (int p = 0; p < 2; p++) {
      __syncthreads();
      if (half == p) {
#pragma unroll
        for (int i = 0; i < 4; i++)
#pragma unroll
          for (int j = 0; j < 4; j++)
#pragma unroll
            for (int r = 0; r < 4; r++)
              osf[((i << 4) + (quad << 2) + r) * 130 + wn + (j << 4) + lr] = acc[i][j][r];
      }
      __syncthreads();
#pragma unroll
      for (int it = 0; it < 8; it++) {
        const int idx = (it << 8) + tid;   // 2048 float4 total
        const int row = idx >> 5;
        const int c4  = (idx & 31) << 2;
        *(float4*)((float*)C + (size_t)(bm + (p << 6) + row) * ldc + bn + c4) =
            *(const float4*)&osf[row * 130 + c4];
      }
    }
  }
}

// ---------------- partial ctxT[e][d] + ksum partial per (chunk,bh) ----------------
// Round-0 structure (tc=32, 1024 blocks) + next-slab register prefetch issued
// under the compute phase so the strided global load latency hides.
__global__ __launch_bounds__(256) void kv_context(const unsigned short* __restrict__ qkv,
                                                  float* __restrict__ part,
                                                  float* __restrict__ ksp) {
  const int bid = blockIdx.x;          // bh(32) x tc(32), tc-fast
  const int tc  = bid & 31;
  const int bh  = bid >> 5;
  const int b   = bh >> 3, h = bh & 7;
  __shared__ float ks[16 * 64];
  __shared__ float vs[16 * 64];
  const int tid = threadIdx.x;
  const int ty = tid >> 4, tx = tid & 15;
  floatx4 acc[4] = {};
  floatx4 ksacc = {0.f, 0.f, 0.f, 0.f};

  const int si    = tid << 3;
  const int strow = si >> 7;
  const int sw    = si & 127;
  const int t0    = b * TT + tc * 128;
  const unsigned short* gcol = qkv + ((sw < 64) ? (512 + h * 64 + sw)
                                                : (1024 + h * 64 + (sw - 64)));
  float* sdst = (sw < 64) ? &ks[strow * 64 + sw] : &vs[strow * 64 + (sw - 64)];

  uint4 raw = *(const uint4*)(gcol + (size_t)(t0 + strow) * NQKV);
  for (int tt = 0; tt < 128; tt += 16) {
    __syncthreads();                         // previous round's LDS readers done
    const floatx4 f0 = {blo(raw.x), bhi(raw.x), blo(raw.y), bhi(raw.y)};
    const floatx4 f1 = {blo(raw.z), bhi(raw.z), blo(raw.w), bhi(raw.w)};
    *(floatx4*)sdst = f0;
    *(floatx4*)(sdst + 4) = f1;
    __syncthreads();
    if (tt + 16 < 128)                       // prefetch next slab under compute
      raw = *(const uint4*)(gcol + (size_t)(t0 + tt + 16 + strow) * NQKV);
#pragma unroll
    for (int t = 0; t < 16; t++) {
      const floatx4 vb = *(const floatx4*)&vs[t * 64 + (ty << 2)];  // 4 e's
      const floatx4 kb = *(const floatx4*)&ks[t * 64 + (tx << 2)];  // 4 d's
      acc[0] += vb.x * kb;
      acc[1] += vb.y * kb;
      acc[2] += vb.z * kb;
      acc[3] += vb.w * kb;
    }
    ksacc += *(const floatx4*)&ks[ty * 64 + (tx << 2)];  // token t==ty slice
  }
  // reduce ksacc across ty via LDS (vs is dead)
  __syncthreads();
  *(floatx4*)&vs[ty * 64 + (tx << 2)] = ksacc;
  __syncthreads();

  float* pg = part + ((size_t)(tc * 32 + bh) << 12) + (size_t)(ty << 2) * 64 + (tx << 2);
#pragma unroll
  for (int i = 0; i < 4; i++)
    *(floatx4*)(pg + i * 64) = acc[i];

  if (tid < 64) {
    float s = 0.f;
    for (int t2 = 0; t2 < 16; t2++) s += vs[t2 * 64 + tid];
    ksp[(tc * 32 + bh) * 64 + tid] = s;
  }
}

// ---------------- reduce partials -> ctxb bf16 [bh][80][64] ----------------
// rows 0-63 = ctxT, row 64 = ksum, rows 65-79 = 0
__global__ __launch_bounds__(256) void ctx_reduce(const float* __restrict__ part,
                                                  const float* __restrict__ ksp,
                                                  unsigned short* __restrict__ ctxb) {
  const int bh = blockIdx.x / 5, g = blockIdx.x % 5;
  const int row = (g << 4) + (threadIdx.x >> 4);
  const int d0  = (threadIdx.x & 15) << 2;
  floatx4 s = {0.f, 0.f, 0.f, 0.f};
  if (row < 64) {
    const float* p = part + ((size_t)bh << 12) + row * 64 + d0;
    for (int c = 0; c < 32; c++)
      s += *(const floatx4*)(p + ((size_t)c << 17));
  } else if (row == 64) {
    const float* p = ksp + bh * 64 + d0;
    for (int c = 0; c < 32; c++)
      s += *(const floatx4*)(p + (c << 11));
  }
  ushort4 o;
  o.x = f2b(s.x); o.y = f2b(s.y); o.z = f2b(s.z); o.w = f2b(s.w);
  *(ushort4*)&ctxb[(size_t)bh * 5120 + (row << 6) + d0] = o;
}

// ---------------- attn_out via MFMA: outT[e][t] = ctxT[e][:]·q'[t][:] ----------------
__global__ __launch_bounds__(256) void attn_out(const unsigned short* __restrict__ qkv,
                                                const unsigned short* __restrict__ ctxb,
                                                unsigned short* __restrict__ opre) {
  const int tc = blockIdx.x >> 5;      // bh-fast
  const int bh = blockIdx.x & 31;
  const int b = bh >> 3, h = bh & 7;
  const int t0 = b * TT + (tc << 6);
  __shared__ unsigned short sh[144 * 72];   // qs[64][72] | cs[80][72] (cs reused as os)
  unsigned short* qs = sh;
  unsigned short* cs = sh + 64 * 72;
  unsigned short* os = cs;
  const int tid = threadIdx.x;

  for (int i = tid; i < 512; i += 256) {
    const int row = i >> 3, c8 = (i & 7) << 3;
    *(uint4*)&qs[row * 72 + c8] =
        *(const uint4*)&qkv[(size_t)(t0 + row) * NQKV + h * 64 + c8];
  }
  for (int i = tid; i < 640; i += 256) {
    const int row = i >> 3, c8 = (i & 7) << 3;
    *(uint4*)&cs[row * 72 + c8] =
        *(const uint4*)&ctxb[(size_t)bh * 5120 + (row << 6) + c8];
  }
  __syncthreads();

  const int lane = tid & 63, w = tid >> 6, quad = lane >> 4, lr = lane & 15;
  floatx4 acc[5] = {};
#pragma unroll
  for (int k2 = 0; k2 < 2; k2++) {
    const int d0 = (k2 << 5) + (quad << 3);
    const frag8 bf = *(const frag8*)&qs[((w << 4) + lr) * 72 + d0];
#pragma unroll
    for (int et = 0; et < 5; et++) {
      const frag8 af = *(const frag8*)&cs[(et * 16 + lr) * 72 + d0];
      acc[et] = __builtin_amdgcn_mfma_f32_16x16x32_bf16(af, bf, acc[et], 0, 0, 0);
    }
  }
  const float dinv = 1.f / __shfl(acc[4][0], lr);
  __syncthreads();                      // done reading cs; reuse as os

  const int trow = (w << 4) + lr;
#pragma unroll
  for (int et = 0; et < 4; et++)
#pragma unroll
    for (int r = 0; r < 4; r++) {
      const int e = et * 16 + (quad << 2) + r;
      const float qv = b2f(qs[trow * 72 + e]);
      os[trow * 72 + e] = f2b(acc[et][r] * dinv + qv);
    }
  __syncthreads();

  for (int i = tid; i < 512; i += 256) {
    const int row = i >> 3, c8 = (i & 7) << 3;
    *(uint4*)&opre[(size_t)(t0 + row) * KDIM + h * 64 + c8] = *(const uint4*)&os[row * 72 + c8];
  }
}

// ---------------- launch ----------------
extern "C" void kernel_launch(void* const* d_in, const int* in_sizes, int n_in,
                              void* d_out, int out_size, void* d_ws, size_t ws_size,
                              hipStream_t stream) {
  (void)in_sizes; (void)n_in; (void)out_size; (void)ws_size;
  const float* x  = (const float*)d_in[0];
  const float* Wq = (const float*)d_in[1];
  const float* bq = (const float*)d_in[2];
  const float* Wk = (const float*)d_in[3];
  const float* bk = (const float*)d_in[4];
  const float* Wv = (const float*)d_in[5];
  const float* bv = (const float*)d_in[6];
  const float* Wp = (const float*)d_in[7];
  const float* bp = (const float*)d_in[8];

  char* w = (char*)d_ws;
  unsigned short* xb   = (unsigned short*)w; w += (size_t)NTOK * KDIM * 2;   // 16 MB
  float* part          = (float*)xb;         // alias: xb dead after qkv GEMM
  unsigned short* wqkv = (unsigned short*)w; w += (size_t)NQKV * KDIM * 2;   // 1.5 MB
  unsigned short* wp   = (unsigned short*)w; w += (size_t)KDIM * KDIM * 2;   // 0.5 MB
  float* bias_qkv      = (float*)w;          w += (size_t)NQKV * 4;          // 6 KB
  float* ksp           = (float*)w;          w += (size_t)1024 * 64 * 4;     // 256 KB
  unsigned short* ctxb = (unsigned short*)w; w += (size_t)32 * 80 * 64 * 2;  // 320 KB
  unsigned short* qkv  = (unsigned short*)w; w += (size_t)NTOK * NQKV * 2;   // 48 MB
  unsigned short* opre = (unsigned short*)w; w += (size_t)NTOK * KDIM * 2;   // 16 MB

  cvt_all<<<9222, 256, 0, stream>>>(x, Wq, Wk, Wv, Wp, bq, bk, bv,
                                    xb, wqkv, wp, bias_qkv);
  gemm_bt<1><<<(NTOK / 128) * (NQKV / 128), 256, 0, stream>>>(
      xb, wqkv, bias_qkv, qkv, NTOK, NQKV, KDIM, NQKV);
  kv_context<<<1024, 256, 0, stream>>>(qkv, part, ksp);
  ctx_reduce<<<160, 256, 0, stream>>>(part, ksp, ctxb);
  attn_out<<<2048, 256, 0, stream>>>(qkv, ctxb, opre);
  gemm_bt<0><<<(NTOK / 128) * (KDIM / 128), 256, 0, stream>>>(
      opre, wp, bp, d_out, NTOK, KDIM, KDIM, KDIM);
}

// Round 7
// 174.615 us; speedup vs baseline: 2.1363x; 1.0148x over previous
//
#include <hip/hip_runtime.h>

#define NTOK  16384   // B*T
#define KDIM  512
#define NQKV  1536
#define TT    4096

using frag8   = __attribute__((ext_vector_type(8))) short;
using floatx4 = __attribute__((ext_vector_type(4))) float;

__device__ __forceinline__ unsigned short f2b(float f) {
  union { float f; unsigned u; } v; v.f = f;
  unsigned r = v.u + 0x7fffu + ((v.u >> 16) & 1u);
  return (unsigned short)(r >> 16);
}
__device__ __forceinline__ float b2f(unsigned short s) {
  union { unsigned u; float f; } v; v.u = ((unsigned)s) << 16; return v.f;
}
__device__ __forceinline__ float blo(unsigned w) {
  union { unsigned u; float f; } v; v.u = w << 16; return v.f;
}
__device__ __forceinline__ float bhi(unsigned w) {
  union { unsigned u; float f; } v; v.u = w & 0xffff0000u; return v.f;
}

__device__ __forceinline__ void gl_lds16(const void* g, void* l) {
  __builtin_amdgcn_global_load_lds((__attribute__((address_space(1))) const void*)g,
                                   (__attribute__((address_space(3))) void*)l,
                                   16, 0, 0);
}
__device__ __forceinline__ floatx4 mfma16(frag8 a, frag8 b, floatx4 c) {
  return __builtin_amdgcn_mfma_f32_16x16x32_bf16(a, b, c, 0, 0, 0);
}

// ---------------- fused convert: x -> bf16, weights -> bf16 (float4), bias concat --------
__global__ __launch_bounds__(256) void cvt_all(
    const float* __restrict__ x,
    const float* __restrict__ Wq, const float* __restrict__ Wk,
    const float* __restrict__ Wv, const float* __restrict__ Wp,
    const float* __restrict__ bq, const float* __restrict__ bk,
    const float* __restrict__ bv,
    unsigned short* __restrict__ xb,
    unsigned short* __restrict__ wqkv, unsigned short* __restrict__ wp,
    float* __restrict__ bias_qkv) {
  const int blk = blockIdx.x;
  if (blk < 8192) {                          // x: 8.4M floats, float4 per thread
    const size_t i = (size_t)blk * 256 + threadIdx.x;
    const float4 v = ((const float4*)x)[i];
    ushort4 o;
    o.x = f2b(v.x); o.y = f2b(v.y); o.z = f2b(v.z); o.w = f2b(v.w);
    ((ushort4*)xb)[i] = o;
    return;
  }
  int idx = (blk - 8192) * 256 + threadIdx.x;
  if (idx < 196608) {                       // wqkv: 1536 rows x 128 float4
    const int m = idx >> 7, c4 = (idx & 127) << 2;
    const float* W = (m < 512) ? Wq : ((m < 1024) ? Wk : Wv);
    const float4 v = *(const float4*)&W[(m & 511) * 512 + c4];
    ushort4 o;
    o.x = f2b(v.x); o.y = f2b(v.y); o.z = f2b(v.z); o.w = f2b(v.w);
    *(ushort4*)&wqkv[m * 512 + c4] = o;
    return;
  }
  idx -= 196608;
  if (idx < 65536) {                        // wp: 65536 float4
    const float4 v = ((const float4*)Wp)[idx];
    ushort4 o;
    o.x = f2b(v.x); o.y = f2b(v.y); o.z = f2b(v.z); o.w = f2b(v.w);
    ((ushort4*)wp)[idx] = o;
    return;
  }
  idx -= 65536;
  if (idx < 1536)
    bias_qkv[idx] = (idx < 512) ? bq[idx]
                  : ((idx < 1024) ? bk[idx - 512] : bv[idx - 1024]);
}

// ---------------- bf16 GEMM, B^T input, XCD-swizzled, BK=64 + XOR LDS swizzle ----------------
// Verified round-0 K-loop (128x128 tile, 4 waves, single-buffered staging, __syncthreads).
// SOFT=1 epilogue by region (block-uniform, 512%128==0):
//   region 0 (q): softmax + padded-LDS repack -> C (q_buf, ldc=512)
//   region 1 (k): softmax + TRANSPOSED repack -> kt[bh][64 d][4096 t]
//   region 2 (v): TRANSPOSED repack -> vt[bh][64 e][4096 t]
// SOFT=0: fp32 store + bias via padded-LDS float4 repack.
template<int SOFT>
__global__ __launch_bounds__(256, 2) void gemm_bt(
    const unsigned short* __restrict__ A,
    const unsigned short* __restrict__ Bm,
    const float* __restrict__ bias,
    void* __restrict__ C,
    unsigned short* __restrict__ kt,
    unsigned short* __restrict__ vt,
    int M, int N, int K, int ldc)
{
  __shared__ unsigned short sh[16640];
  unsigned short* As = sh;
  unsigned short* Bs = sh + 128 * 64;
  const int tid  = threadIdx.x;
  const int wave = tid >> 6;
  const int lane = tid & 63;
  const int quad = lane >> 4;
  const int lr   = lane & 15;
  const int sw7  = lr & 7;
  // XCD swizzle: keep all n-tiles of an m-tile on one XCD (L2 A-reuse)
  const int bid  = ((blockIdx.x & 7) * (gridDim.x >> 3)) + (blockIdx.x >> 3);
  const int nt   = N >> 7;
  const int bn   = (bid % nt) << 7;
  const int bm   = (bid / nt) << 7;
  const int half = wave >> 1;
  const int wm   = half << 6;
  const int wn   = (wave & 1) << 6;

  floatx4 acc[4][4] = {};

  const int srow = tid >> 3;
  const int scol = ((tid & 7) ^ ((tid >> 3) & 7)) << 3;
  const unsigned short* Ag = A + (size_t)(bm + srow) * K + scol;
  const unsigned short* Bg = Bm + (size_t)(bn + srow) * K + scol;
  unsigned short* Al = As + (wave << 9);
  unsigned short* Bl = Bs + (wave << 9);

  for (int k0 = 0; k0 < K; k0 += 64) {
    __syncthreads();
    gl_lds16(Ag + k0,                    Al);
    gl_lds16(Ag + (size_t)32 * K + k0,   Al + 2048);
    gl_lds16(Ag + (size_t)64 * K + k0,   Al + 4096);
    gl_lds16(Ag + (size_t)96 * K + k0,   Al + 6144);
    gl_lds16(Bg + k0,                    Bl);
    gl_lds16(Bg + (size_t)32 * K + k0,   Bl + 2048);
    gl_lds16(Bg + (size_t)64 * K + k0,   Bl + 4096);
    gl_lds16(Bg + (size_t)96 * K + k0,   Bl + 6144);
    __syncthreads();

#pragma unroll
    for (int kk = 0; kk < 2; kk++) {
      const int coff = ((((kk << 2) + quad) ^ sw7) << 3);
      frag8 af[4], bf[4];
#pragma unroll
      for (int i = 0; i < 4; i++)
        af[i] = *(const frag8*)&As[(wm + (i << 4) + lr) * 64 + coff];
#pragma unroll
      for (int j = 0; j < 4; j++)
        bf[j] = *(const frag8*)&Bs[(wn + (j << 4) + lr) * 64 + coff];
#pragma unroll
      for (int i = 0; i < 4; i++)
#pragma unroll
        for (int j = 0; j < 4; j++)
          acc[i][j] = mfma16(af[i], bf[j], acc[i][j]);
    }
  }

  // epilogue: C/D layout col=lane&15, row=quad*4+reg
  const int ccol0 = bn + wn + lr;

#pragma unroll
  for (int j = 0; j < 4; j++) {
    const float bv = bias[ccol0 + (j << 4)];
#pragma unroll
    for (int i = 0; i < 4; i++)
#pragma unroll
      for (int r = 0; r < 4; r++)
        acc[i][j][r] += bv;
  }

  if (SOFT) {
    const int region = bn >> 9;          // 0=q, 1=k, 2=v (block-uniform: 512 % 128 == 0)
    if (region < 2) {
#pragma unroll
      for (int i = 0; i < 4; i++)
#pragma unroll
        for (int r = 0; r < 4; r++) {
          float e0 = __expf(acc[i][0][r]);
          float e1 = __expf(acc[i][1][r]);
          float e2 = __expf(acc[i][2][r]);
          float e3 = __expf(acc[i][3][r]);
          float s = e0 + e1 + e2 + e3;
          s += __shfl_xor(s, 1);
          s += __shfl_xor(s, 2);
          s += __shfl_xor(s, 4);
          s += __shfl_xor(s, 8);
          const float inv = 1.f / s;
          acc[i][0][r] = e0 * inv; acc[i][1][r] = e1 * inv;
          acc[i][2][r] = e2 * inv; acc[i][3][r] = e3 * inv;
        }
    }
    if (region == 0) {
      // q: coalesced bf16 store via padded LDS repack (stride 132), ldc = 512
      unsigned short* os = sh;
#pragma unroll
      for (int p = 0; p < 2; p++) {
        __syncthreads();
        if (half == p) {
#pragma unroll
          for (int i = 0; i < 4; i++)
#pragma unroll
            for (int j = 0; j < 4; j++)
#pragma unroll
              for (int r = 0; r < 4; r++)
                os[((i << 4) + (quad << 2) + r) * 132 + wn + (j << 4) + lr] = f2b(acc[i][j][r]);
        }
        __syncthreads();
#pragma unroll
        for (int it = 0; it < 4; it++) {
          const int idx = (it << 8) + tid;   // 1024 uint4 total
          const int row = idx >> 4;
          const int c8  = (idx & 15) << 3;
          *(uint4*)((unsigned short*)C + (size_t)(bm + (p << 6) + row) * ldc + bn + c8) =
              *(const uint4*)&os[row * 132 + c8];
        }
      }
    } else {
      // k/v: transposed store -> T[bh][d][4096 t]. Pass p handles the 64 cols of
      // waves with wn == p*64 (one head exactly). osT [64 cols][130 rows-stride].
      unsigned short* T = (region == 1) ? kt : vt;
      const int b   = bm >> 12;
      const int tIn = bm & 4095;
      unsigned short* osT = sh;
#pragma unroll
      for (int p = 0; p < 2; p++) {
        __syncthreads();
        if ((wave & 1) == p) {
#pragma unroll
          for (int i = 0; i < 4; i++)
#pragma unroll
            for (int j = 0; j < 4; j++)
#pragma unroll
              for (int r = 0; r < 4; r++)
                osT[((j << 4) + lr) * 130 + wm + (i << 4) + (quad << 2) + r] =
                    f2b(acc[i][j][r]);
        }
        __syncthreads();
        const int hh = ((bn >> 6) + p) & 7;
        unsigned short* Tb = T + (((size_t)(b << 3) + hh) << 18) + tIn;
#pragma unroll
        for (int it = 0; it < 4; it++) {
          const int idx = (it << 8) + tid;   // 1024 uint4: 64 cols x 16 token-groups
          const int col = idx >> 4;          // d
          const int tg  = (idx & 15) << 3;
          *(uint4*)&Tb[((size_t)col << 12) + tg] = *(const uint4*)&osT[col * 130 + tg];
        }
      }
    }
  } else {
    // coalesced fp32 store via padded LDS repack (stride 130 floats: conflict-free)
    float* osf = (float*)sh;
#pragma unroll
    for (int p = 0; p < 2; p++) {
      __syncthreads();
      if (half == p) {
#pragma unroll
        for (int i = 0; i < 4; i++)
#pragma unroll
          for (int j = 0; j < 4; j++)
#pragma unroll
            for (int r = 0; r < 4; r++)
              osf[((i << 4) + (quad << 2) + r) * 130 + wn + (j << 4) + lr] = acc[i][j][r];
      }
      __syncthreads();
#pragma unroll
      for (int it = 0; it < 8; it++) {
        const int idx = (it << 8) + tid;   // 2048 float4 total
        const int row = idx >> 5;
        const int c4  = (idx & 31) << 2;
        *(float4*)((float*)C + (size_t)(bm + (p << 6) + row) * ldc + bn + c4) =
            *(const float4*)&osf[row * 130 + c4];
      }
    }
  }
}

// ---------------- kv_context via MFMA: part[chunk][d][e] = sum_t k[t][d] v[t][e] ------------
// kT/vT are [bh][64][4096] (d-major) so BOTH operands are native row-major-K-contiguous:
// A = vT rows (A[e][t]), B^T = kT rows (B[t][d]). Single-staged LDS (32 KB), one
// __syncthreads, 16 MFMA/wave, 4 waves. XOR chunk-swizzle identical to gemm_bt.
// ksum from kT-tile row-sums. part layout [d*64+e] (column-major of D) -> float4 stores.
__global__ __launch_bounds__(256) void kv_context(const unsigned short* __restrict__ kt,
                                                  const unsigned short* __restrict__ vt,
                                                  float* __restrict__ part,
                                                  float* __restrict__ ksp) {
  const int bid = blockIdx.x;          // bh(32) x tc(32), tc-fast
  const int tc  = bid & 31;
  const int bh  = bid >> 5;
  __shared__ unsigned short sh[16384]; // vsl[64][128] | ksl[64][128], swizzled
  unsigned short* vsl = sh;
  unsigned short* ksl = sh + 8192;
  const int tid  = threadIdx.x;
  const int wave = tid >> 6;
  const int lane = tid & 63;
  const int quad = lane >> 4;
  const int lr   = lane & 15;
  const int t0   = tc << 7;

  // staging: per gl_lds16 a wave covers 4 rows x 16 chunks; lane l -> row +(l>>4),
  // LDS chunk l&15 holding global chunk (l&15)^(row&7) (source pre-swizzle).
  const int lrow = lane >> 4;
  const int lchk = lane & 15;
  const unsigned short* vg = vt + ((size_t)bh << 18) + t0;
  const unsigned short* kg = kt + ((size_t)bh << 18) + t0;
#pragma unroll
  for (int i = 0; i < 4; i++) {
    const int rb  = (wave << 4) + (i << 2);           // wave-uniform row base
    const int row = rb + lrow;                        // per-lane row
    const int sc  = (lchk ^ (row & 7)) << 3;          // swizzled col (shorts)
    gl_lds16(vg + ((size_t)row << 12) + sc, vsl + (rb << 7));
    gl_lds16(kg + ((size_t)row << 12) + sc, ksl + (rb << 7));
  }
  __syncthreads();

  // MFMA: wave computes e-rows [we, we+16) x all 64 d
  floatx4 acc[4] = {};
  const int we = wave << 4;
#pragma unroll
  for (int ks = 0; ks < 4; ks++) {
    const int co = ((((ks << 2) + quad) ^ (lr & 7)) << 3);
    const frag8 af = *(const frag8*)&vsl[(we + lr) * 128 + co];
    frag8 bfr[4];
#pragma unroll
    for (int j = 0; j < 4; j++)
      bfr[j] = *(const frag8*)&ksl[((j << 4) + lr) * 128 + co];
#pragma unroll
    for (int j = 0; j < 4; j++)
      acc[j] = mfma16(af, bfr[j], acc[j]);
  }

  // part store: D[e][d] element (lane,j,r): e = we+quad*4+r, d = j*16+lr.
  // layout [d*64+e]: float4 along e (r) is contiguous.
  float* pg = part + ((size_t)(tc * 32 + bh) << 12) + we + (quad << 2);
#pragma unroll
  for (int j = 0; j < 4; j++)
    *(floatx4*)&pg[((j << 4) + lr) << 6] = acc[j];

  // ksum: row-sums of kT-tile (128 t per row), 4 threads per d-row
  const int r2 = tid >> 2;
  const int q4 = tid & 3;
  float s = 0.f;
#pragma unroll
  for (int c = 0; c < 4; c++) {
    const int ch = ((q4 << 2) + c) ^ (r2 & 7);
    const uint4 raw = *(const uint4*)&ksl[r2 * 128 + (ch << 3)];
    s += blo(raw.x) + bhi(raw.x) + blo(raw.y) + bhi(raw.y)
       + blo(raw.z) + bhi(raw.z) + blo(raw.w) + bhi(raw.w);
  }
  s += __shfl_xor(s, 1);
  s += __shfl_xor(s, 2);
  if (q4 == 0) ksp[(tc * 32 + bh) * 64 + r2] = s;
}

// ---------------- reduce partials -> ctxb bf16 [bh][80][64] ----------------
// part rows are d (layout [d][e]); ctxb rows 0-63 = ctxT[e][d] (transposed write),
// row 64 = ksum[d], rows 65-79 = 0.
__global__ __launch_bounds__(256) void ctx_reduce(const float* __restrict__ part,
                                                  const float* __restrict__ ksp,
                                                  unsigned short* __restrict__ ctxb) {
  const int bh = blockIdx.x / 5, g = blockIdx.x % 5;
  const int row = (g << 4) + (threadIdx.x >> 4);    // d for rows<64
  const int d0  = (threadIdx.x & 15) << 2;          // e-range for rows<64
  floatx4 s = {0.f, 0.f, 0.f, 0.f};
  if (row < 64) {
    const float* p = part + ((size_t)bh << 12) + (row << 6) + d0;
    for (int c = 0; c < 32; c++)
      s += *(const floatx4*)(p + ((size_t)c << 17));
#pragma unroll
    for (int i = 0; i < 4; i++)
      ctxb[(size_t)bh * 5120 + ((size_t)(d0 + i) << 6) + row] = f2b(s[i]);
  } else {
    if (row == 64) {
      const float* p = ksp + bh * 64 + d0;
      for (int c = 0; c < 32; c++)
        s += *(const floatx4*)(p + (c << 11));
    }
    ushort4 o;
    o.x = f2b(s.x); o.y = f2b(s.y); o.z = f2b(s.z); o.w = f2b(s.w);
    *(ushort4*)&ctxb[(size_t)bh * 5120 + (row << 6) + d0] = o;
  }
}

// ---------------- attn_out via MFMA: outT[e][t] = ctxT[e][:]·q'[t][:] ----------------
__global__ __launch_bounds__(256) void attn_out(const unsigned short* __restrict__ qb,
                                                const unsigned short* __restrict__ ctxb,
                                                unsigned short* __restrict__ opre) {
  const int tc = blockIdx.x >> 5;      // bh-fast
  const int bh = blockIdx.x & 31;
  const int b = bh >> 3, h = bh & 7;
  const int t0 = b * TT + (tc << 6);
  __shared__ unsigned short sh[144 * 72];   // qs[64][72] | cs[80][72] (cs reused as os)
  unsigned short* qs = sh;
  unsigned short* cs = sh + 64 * 72;
  unsigned short* os = cs;
  const int tid = threadIdx.x;

  for (int i = tid; i < 512; i += 256) {
    const int row = i >> 3, c8 = (i & 7) << 3;
    *(uint4*)&qs[row * 72 + c8] =
        *(const uint4*)&qb[(size_t)(t0 + row) * KDIM + h * 64 + c8];
  }
  for (int i = tid; i < 640; i += 256) {
    const int row = i >> 3, c8 = (i & 7) << 3;
    *(uint4*)&cs[row * 72 + c8] =
        *(const uint4*)&ctxb[(size_t)bh * 5120 + (row << 6) + c8];
  }
  __syncthreads();

  const int lane = tid & 63, w = tid >> 6, quad = lane >> 4, lr = lane & 15;
  floatx4 acc[5] = {};
#pragma unroll
  for (int k2 = 0; k2 < 2; k2++) {
    const int d0 = (k2 << 5) + (quad << 3);
    const frag8 bf = *(const frag8*)&qs[((w << 4) + lr) * 72 + d0];
#pragma unroll
    for (int et = 0; et < 5; et++) {
      const frag8 af = *(const frag8*)&cs[(et * 16 + lr) * 72 + d0];
      acc[et] = mfma16(af, bf, acc[et]);
    }
  }
  const float dinv = 1.f / __shfl(acc[4][0], lr);
  __syncthreads();                      // done reading cs; reuse as os

  const int trow = (w << 4) + lr;
#pragma unroll
  for (int et = 0; et < 4; et++)
#pragma unroll
    for (int r = 0; r < 4; r++) {
      const int e = et * 16 + (quad << 2) + r;
      const float qv = b2f(qs[trow * 72 + e]);
      os[trow * 72 + e] = f2b(acc[et][r] * dinv + qv);
    }
  __syncthreads();

  for (int i = tid; i < 512; i += 256) {
    const int row = i >> 3, c8 = (i & 7) << 3;
    *(uint4*)&opre[(size_t)(t0 + row) * KDIM + h * 64 + c8] = *(const uint4*)&os[row * 72 + c8];
  }
}

// ---------------- launch ----------------
extern "C" void kernel_launch(void* const* d_in, const int* in_sizes, int n_in,
                              void* d_out, int out_size, void* d_ws, size_t ws_size,
                              hipStream_t stream) {
  (void)in_sizes; (void)n_in; (void)out_size; (void)ws_size;
  const float* x  = (const float*)d_in[0];
  const float* Wq = (const float*)d_in[1];
  const float* bq = (const float*)d_in[2];
  const float* Wk = (const float*)d_in[3];
  const float* bk = (const float*)d_in[4];
  const float* Wv = (const float*)d_in[5];
  const float* bv = (const float*)d_in[6];
  const float* Wp = (const float*)d_in[7];
  const float* bp = (const float*)d_in[8];

  char* w = (char*)d_ws;
  unsigned short* xb   = (unsigned short*)w; w += (size_t)NTOK * KDIM * 2;   // 16 MB
  float* part          = (float*)xb;         // alias: xb dead after qkv GEMM
  unsigned short* wqkv = (unsigned short*)w; w += (size_t)NQKV * KDIM * 2;   // 1.5 MB
  unsigned short* wp   = (unsigned short*)w; w += (size_t)KDIM * KDIM * 2;   // 0.5 MB
  float* bias_qkv      = (float*)w;          w += (size_t)NQKV * 4;          // 6 KB
  float* ksp           = (float*)w;          w += (size_t)1024 * 64 * 4;     // 256 KB
  unsigned short* ctxb = (unsigned short*)w; w += (size_t)32 * 80 * 64 * 2;  // 320 KB
  unsigned short* qkv  = (unsigned short*)w; w += (size_t)NTOK * NQKV * 2;   // 48 MB
  unsigned short* opre = (unsigned short*)w; w += (size_t)NTOK * KDIM * 2;   // 16 MB

  unsigned short* qb  = qkv;                               // 16 MB [t][512]
  unsigned short* ktb = qkv + (size_t)NTOK * 512;          // 16 MB [bh][64][4096]
  unsigned short* vtb = ktb + (size_t)32 * 64 * TT;        // 16 MB [bh][64][4096]

  cvt_all<<<9222, 256, 0, stream>>>(x, Wq, Wk, Wv, Wp, bq, bk, bv,
                                    xb, wqkv, wp, bias_qkv);
  gemm_bt<1><<<(NTOK / 128) * (NQKV / 128), 256, 0, stream>>>(
      xb, wqkv, bias_qkv, qb, ktb, vtb, NTOK, NQKV, KDIM, 512);
  kv_context<<<1024, 256, 0, stream>>>(ktb, vtb, part, ksp);
  ctx_reduce<<<160, 256, 0, stream>>>(part, ksp, ctxb);
  attn_out<<<2048, 256, 0, stream>>>(qb, ctxb, opre);
  gemm_bt<0><<<(NTOK / 128) * (KDIM / 128), 256, 0, stream>>>(
      opre, wp, bp, d_out, nullptr, nullptr, NTOK, KDIM, KDIM, KDIM);
}

// Round 8
// 173.775 us; speedup vs baseline: 2.1466x; 1.0048x over previous
//
#include <hip/hip_runtime.h>

#define NTOK  16384   // B*T
#define KDIM  512
#define NQKV  1536
#define TT    4096

using frag8   = __attribute__((ext_vector_type(8))) short;
using floatx4 = __attribute__((ext_vector_type(4))) float;

__device__ __forceinline__ unsigned short f2b(float f) {
  union { float f; unsigned u; } v; v.f = f;
  unsigned r = v.u + 0x7fffu + ((v.u >> 16) & 1u);
  return (unsigned short)(r >> 16);
}
__device__ __forceinline__ float b2f(unsigned short s) {
  union { unsigned u; float f; } v; v.u = ((unsigned)s) << 16; return v.f;
}
__device__ __forceinline__ float blo(unsigned w) {
  union { unsigned u; float f; } v; v.u = w << 16; return v.f;
}
__device__ __forceinline__ float bhi(unsigned w) {
  union { unsigned u; float f; } v; v.u = w & 0xffff0000u; return v.f;
}

__device__ __forceinline__ void gl_lds16(const void* g, void* l) {
  __builtin_amdgcn_global_load_lds((__attribute__((address_space(1))) const void*)g,
                                   (__attribute__((address_space(3))) void*)l,
                                   16, 0, 0);
}
__device__ __forceinline__ floatx4 mfma16(frag8 a, frag8 b, floatx4 c) {
  return __builtin_amdgcn_mfma_f32_16x16x32_bf16(a, b, c, 0, 0, 0);
}

// ---------------- fused convert: x -> bf16, weights -> bf16 (float4), bias concat --------
__global__ __launch_bounds__(256) void cvt_all(
    const float* __restrict__ x,
    const float* __restrict__ Wq, const float* __restrict__ Wk,
    const float* __restrict__ Wv, const float* __restrict__ Wp,
    const float* __restrict__ bq, const float* __restrict__ bk,
    const float* __restrict__ bv,
    unsigned short* __restrict__ xb,
    unsigned short* __restrict__ wqkv, unsigned short* __restrict__ wp,
    float* __restrict__ bias_qkv) {
  const int blk = blockIdx.x;
  if (blk < 8192) {                          // x: 8.4M floats, float4 per thread
    const size_t i = (size_t)blk * 256 + threadIdx.x;
    const float4 v = ((const float4*)x)[i];
    ushort4 o;
    o.x = f2b(v.x); o.y = f2b(v.y); o.z = f2b(v.z); o.w = f2b(v.w);
    ((ushort4*)xb)[i] = o;
    return;
  }
  int idx = (blk - 8192) * 256 + threadIdx.x;
  if (idx < 196608) {                       // wqkv: 1536 rows x 128 float4
    const int m = idx >> 7, c4 = (idx & 127) << 2;
    const float* W = (m < 512) ? Wq : ((m < 1024) ? Wk : Wv);
    const float4 v = *(const float4*)&W[(m & 511) * 512 + c4];
    ushort4 o;
    o.x = f2b(v.x); o.y = f2b(v.y); o.z = f2b(v.z); o.w = f2b(v.w);
    *(ushort4*)&wqkv[m * 512 + c4] = o;
    return;
  }
  idx -= 196608;
  if (idx < 65536) {                        // wp: 65536 float4
    const float4 v = ((const float4*)Wp)[idx];
    ushort4 o;
    o.x = f2b(v.x); o.y = f2b(v.y); o.z = f2b(v.z); o.w = f2b(v.w);
    ((ushort4*)wp)[idx] = o;
    return;
  }
  idx -= 65536;
  if (idx < 1536)
    bias_qkv[idx] = (idx < 512) ? bq[idx]
                  : ((idx < 1024) ? bk[idx - 512] : bv[idx - 1024]);
}

// ---------------- bf16 GEMM, B^T input, XCD-swizzled, BK=64 + XOR LDS swizzle ----------------
// Verified round-0 K-loop (128x128 tile, 4 waves, single-buffered staging, __syncthreads).
// LDS capped at exactly 32 KB -> 5 blocks/CU (fp32 repack runs in 4 passes of 32 rows).
// SOFT=1 epilogue by region (block-uniform, 512%128==0):
//   region 0 (q): softmax + padded-LDS repack -> C (q_buf, ldc=512)
//   region 1 (k): softmax + TRANSPOSED repack -> kt[bh][64 d][4096 t]
//   region 2 (v): TRANSPOSED repack -> vt[bh][64 e][4096 t]
// SOFT=0: fp32 store + bias via padded-LDS float4 repack (4 passes).
template<int SOFT>
__global__ __launch_bounds__(256, 2) void gemm_bt(
    const unsigned short* __restrict__ A,
    const unsigned short* __restrict__ Bm,
    const float* __restrict__ bias,
    void* __restrict__ C,
    unsigned short* __restrict__ kt,
    unsigned short* __restrict__ vt,
    int M, int N, int K, int ldc)
{
  __shared__ unsigned short sh[16384];       // 32768 B: staging; epilogue reuses low region
  unsigned short* As = sh;
  unsigned short* Bs = sh + 128 * 64;
  const int tid  = threadIdx.x;
  const int wave = tid >> 6;
  const int lane = tid & 63;
  const int quad = lane >> 4;
  const int lr   = lane & 15;
  const int sw7  = lr & 7;
  // XCD swizzle: keep all n-tiles of an m-tile on one XCD (L2 A-reuse)
  const int bid  = ((blockIdx.x & 7) * (gridDim.x >> 3)) + (blockIdx.x >> 3);
  const int nt   = N >> 7;
  const int bn   = (bid % nt) << 7;
  const int bm   = (bid / nt) << 7;
  const int half = wave >> 1;
  const int wm   = half << 6;
  const int wn   = (wave & 1) << 6;

  floatx4 acc[4][4] = {};

  const int srow = tid >> 3;
  const int scol = ((tid & 7) ^ ((tid >> 3) & 7)) << 3;
  const unsigned short* Ag = A + (size_t)(bm + srow) * K + scol;
  const unsigned short* Bg = Bm + (size_t)(bn + srow) * K + scol;
  unsigned short* Al = As + (wave << 9);
  unsigned short* Bl = Bs + (wave << 9);

  for (int k0 = 0; k0 < K; k0 += 64) {
    __syncthreads();
    gl_lds16(Ag + k0,                    Al);
    gl_lds16(Ag + (size_t)32 * K + k0,   Al + 2048);
    gl_lds16(Ag + (size_t)64 * K + k0,   Al + 4096);
    gl_lds16(Ag + (size_t)96 * K + k0,   Al + 6144);
    gl_lds16(Bg + k0,                    Bl);
    gl_lds16(Bg + (size_t)32 * K + k0,   Bl + 2048);
    gl_lds16(Bg + (size_t)64 * K + k0,   Bl + 4096);
    gl_lds16(Bg + (size_t)96 * K + k0,   Bl + 6144);
    __syncthreads();

#pragma unroll
    for (int kk = 0; kk < 2; kk++) {
      const int coff = ((((kk << 2) + quad) ^ sw7) << 3);
      frag8 af[4], bf[4];
#pragma unroll
      for (int i = 0; i < 4; i++)
        af[i] = *(const frag8*)&As[(wm + (i << 4) + lr) * 64 + coff];
#pragma unroll
      for (int j = 0; j < 4; j++)
        bf[j] = *(const frag8*)&Bs[(wn + (j << 4) + lr) * 64 + coff];
#pragma unroll
      for (int i = 0; i < 4; i++)
#pragma unroll
        for (int j = 0; j < 4; j++)
          acc[i][j] = mfma16(af[i], bf[j], acc[i][j]);
    }
  }

  // epilogue: C/D layout col=lane&15, row=quad*4+reg
  const int ccol0 = bn + wn + lr;

#pragma unroll
  for (int j = 0; j < 4; j++) {
    const float bv = bias[ccol0 + (j << 4)];
#pragma unroll
    for (int i = 0; i < 4; i++)
#pragma unroll
      for (int r = 0; r < 4; r++)
        acc[i][j][r] += bv;
  }

  if (SOFT) {
    const int region = bn >> 9;          // 0=q, 1=k, 2=v (block-uniform: 512 % 128 == 0)
    if (region < 2) {
#pragma unroll
      for (int i = 0; i < 4; i++)
#pragma unroll
        for (int r = 0; r < 4; r++) {
          float e0 = __expf(acc[i][0][r]);
          float e1 = __expf(acc[i][1][r]);
          float e2 = __expf(acc[i][2][r]);
          float e3 = __expf(acc[i][3][r]);
          float s = e0 + e1 + e2 + e3;
          s += __shfl_xor(s, 1);
          s += __shfl_xor(s, 2);
          s += __shfl_xor(s, 4);
          s += __shfl_xor(s, 8);
          const float inv = 1.f / s;
          acc[i][0][r] = e0 * inv; acc[i][1][r] = e1 * inv;
          acc[i][2][r] = e2 * inv; acc[i][3][r] = e3 * inv;
        }
    }
    if (region == 0) {
      // q: coalesced bf16 store via padded LDS repack (stride 132), ldc = 512
      unsigned short* os = sh;
#pragma unroll
      for (int p = 0; p < 2; p++) {
        __syncthreads();
        if (half == p) {
#pragma unroll
          for (int i = 0; i < 4; i++)
#pragma unroll
            for (int j = 0; j < 4; j++)
#pragma unroll
              for (int r = 0; r < 4; r++)
                os[((i << 4) + (quad << 2) + r) * 132 + wn + (j << 4) + lr] = f2b(acc[i][j][r]);
        }
        __syncthreads();
#pragma unroll
        for (int it = 0; it < 4; it++) {
          const int idx = (it << 8) + tid;   // 1024 uint4 total
          const int row = idx >> 4;
          const int c8  = (idx & 15) << 3;
          *(uint4*)((unsigned short*)C + (size_t)(bm + (p << 6) + row) * ldc + bn + c8) =
              *(const uint4*)&os[row * 132 + c8];
        }
      }
    } else {
      // k/v: transposed store -> T[bh][d][4096 t]. Pass p handles the 64 cols of
      // waves with wn == p*64 (one head exactly). osT [64 cols][130 rows-stride].
      unsigned short* T = (region == 1) ? kt : vt;
      const int b   = bm >> 12;
      const int tIn = bm & 4095;
      unsigned short* osT = sh;
#pragma unroll
      for (int p = 0; p < 2; p++) {
        __syncthreads();
        if ((wave & 1) == p) {
#pragma unroll
          for (int i = 0; i < 4; i++)
#pragma unroll
            for (int j = 0; j < 4; j++)
#pragma unroll
              for (int r = 0; r < 4; r++)
                osT[((j << 4) + lr) * 130 + wm + (i << 4) + (quad << 2) + r] =
                    f2b(acc[i][j][r]);
        }
        __syncthreads();
        const int hh = ((bn >> 6) + p) & 7;
        unsigned short* Tb = T + (((size_t)(b << 3) + hh) << 18) + tIn;
#pragma unroll
        for (int it = 0; it < 4; it++) {
          const int idx = (it << 8) + tid;   // 1024 uint4: 64 cols x 16 token-groups
          const int col = idx >> 4;          // d
          const int tg  = (idx & 15) << 3;
          *(uint4*)&Tb[((size_t)col << 12) + tg] = *(const uint4*)&osT[col * 130 + tg];
        }
      }
    }
  } else {
    // fp32 store + bias: 4 passes of 32 rows (32*130 floats = 16640 B <= 32 KB)
    float* osf = (float*)sh;
#pragma unroll
    for (int p2 = 0; p2 < 4; p2++) {
      __syncthreads();
      if (half == (p2 >> 1)) {
#pragma unroll
        for (int i2 = 0; i2 < 2; i2++) {
          const int i = ((p2 & 1) << 1) + i2;
#pragma unroll
          for (int j = 0; j < 4; j++)
#pragma unroll
            for (int r = 0; r < 4; r++)
              osf[((i2 << 4) + (quad << 2) + r) * 130 + wn + (j << 4) + lr] = acc[i][j][r];
        }
      }
      __syncthreads();
#pragma unroll
      for (int it = 0; it < 4; it++) {
        const int idx = (it << 8) + tid;   // 1024 float4: 32 rows x 32 float4
        const int row = idx >> 5;
        const int c4  = (idx & 31) << 2;
        *(float4*)((float*)C +
                   (size_t)(bm + ((p2 >> 1) << 6) + ((p2 & 1) << 5) + row) * ldc + bn + c4) =
            *(const float4*)&osf[row * 130 + c4];
      }
    }
  }
}

// ---------------- kv_context via MFMA: part[chunk][d][e] = sum_t k[t][d] v[t][e] ------------
// kT/vT are [bh][64][4096] (d-major): A = vT rows, B^T = kT rows, both K-contiguous.
// 16 chunks of 256 tokens; each block accumulates 2 sub-tiles of 128 tokens in
// registers (same verified 2-barrier pattern per sub-tile). part layout [d*64+e].
__global__ __launch_bounds__(256) void kv_context(const unsigned short* __restrict__ kt,
                                                  const unsigned short* __restrict__ vt,
                                                  float* __restrict__ part,
                                                  float* __restrict__ ksp) {
  const int bid = blockIdx.x;          // bh(32) x tc(16), tc-fast
  const int tc  = bid & 15;
  const int bh  = bid >> 4;
  __shared__ unsigned short sh[16384]; // vsl[64][128] | ksl[64][128], swizzled
  unsigned short* vsl = sh;
  unsigned short* ksl = sh + 8192;
  const int tid  = threadIdx.x;
  const int wave = tid >> 6;
  const int lane = tid & 63;
  const int quad = lane >> 4;
  const int lr   = lane & 15;

  const int lrow = lane >> 4;
  const int lchk = lane & 15;
  const unsigned short* vg = vt + ((size_t)bh << 18) + (tc << 8);
  const unsigned short* kg = kt + ((size_t)bh << 18) + (tc << 8);

  floatx4 acc[4] = {};
  const int we = wave << 4;
  float s = 0.f;
  const int r2 = tid >> 2;
  const int q4 = tid & 3;

  for (int sub = 0; sub < 2; ++sub) {
    __syncthreads();                    // previous sub-tile's LDS readers done
#pragma unroll
    for (int i = 0; i < 4; i++) {
      const int rb  = (wave << 4) + (i << 2);           // wave-uniform row base
      const int row = rb + lrow;                        // per-lane row
      const int sc  = (lchk ^ (row & 7)) << 3;          // swizzled col (shorts)
      gl_lds16(vg + ((size_t)row << 12) + (sub << 7) + sc, vsl + (rb << 7));
      gl_lds16(kg + ((size_t)row << 12) + (sub << 7) + sc, ksl + (rb << 7));
    }
    __syncthreads();

#pragma unroll
    for (int ks = 0; ks < 4; ks++) {
      const int co = ((((ks << 2) + quad) ^ (lr & 7)) << 3);
      const frag8 af = *(const frag8*)&vsl[(we + lr) * 128 + co];
      frag8 bfr[4];
#pragma unroll
      for (int j = 0; j < 4; j++)
        bfr[j] = *(const frag8*)&ksl[((j << 4) + lr) * 128 + co];
#pragma unroll
      for (int j = 0; j < 4; j++)
        acc[j] = mfma16(af, bfr[j], acc[j]);
    }

    // ksum: row-sums of kT sub-tile (128 t per row), 4 threads per d-row
#pragma unroll
    for (int c = 0; c < 4; c++) {
      const int ch = ((q4 << 2) + c) ^ (r2 & 7);
      const uint4 raw = *(const uint4*)&ksl[r2 * 128 + (ch << 3)];
      s += blo(raw.x) + bhi(raw.x) + blo(raw.y) + bhi(raw.y)
         + blo(raw.z) + bhi(raw.z) + blo(raw.w) + bhi(raw.w);
    }
  }

  // part store: D[e][d] element (lane,j,r): e = we+quad*4+r, d = j*16+lr.
  float* pg = part + ((size_t)(tc * 32 + bh) << 12) + we + (quad << 2);
#pragma unroll
  for (int j = 0; j < 4; j++)
    *(floatx4*)&pg[((j << 4) + lr) << 6] = acc[j];

  s += __shfl_xor(s, 1);
  s += __shfl_xor(s, 2);
  if (q4 == 0) ksp[(tc * 32 + bh) * 64 + r2] = s;
}

// ---------------- reduce partials -> ctxb bf16 [bh][80][64] ----------------
// part rows are d (layout [d][e]); ctxb rows 0-63 = ctxT[e][d] (transposed write),
// row 64 = ksum[d], rows 65-79 = 0.
__global__ __launch_bounds__(256) void ctx_reduce(const float* __restrict__ part,
                                                  const float* __restrict__ ksp,
                                                  unsigned short* __restrict__ ctxb) {
  const int bh = blockIdx.x / 5, g = blockIdx.x % 5;
  const int row = (g << 4) + (threadIdx.x >> 4);    // d for rows<64
  const int d0  = (threadIdx.x & 15) << 2;          // e-range for rows<64
  floatx4 s = {0.f, 0.f, 0.f, 0.f};
  if (row < 64) {
    const float* p = part + ((size_t)bh << 12) + (row << 6) + d0;
    for (int c = 0; c < 16; c++)
      s += *(const floatx4*)(p + ((size_t)c << 17));
#pragma unroll
    for (int i = 0; i < 4; i++)
      ctxb[(size_t)bh * 5120 + ((size_t)(d0 + i) << 6) + row] = f2b(s[i]);
  } else {
    if (row == 64) {
      const float* p = ksp + bh * 64 + d0;
      for (int c = 0; c < 16; c++)
        s += *(const floatx4*)(p + (c << 11));
    }
    ushort4 o;
    o.x = f2b(s.x); o.y = f2b(s.y); o.z = f2b(s.z); o.w = f2b(s.w);
    *(ushort4*)&ctxb[(size_t)bh * 5120 + (row << 6) + d0] = o;
  }
}

// ---------------- attn_out via MFMA: outT[e][t] = ctxT[e][:]·q'[t][:] ----------------
__global__ __launch_bounds__(256) void attn_out(const unsigned short* __restrict__ qb,
                                                const unsigned short* __restrict__ ctxb,
                                                unsigned short* __restrict__ opre) {
  const int tc = blockIdx.x >> 5;      // bh-fast
  const int bh = blockIdx.x & 31;
  const int b = bh >> 3, h = bh & 7;
  const int t0 = b * TT + (tc << 6);
  __shared__ unsigned short sh[144 * 72];   // qs[64][72] | cs[80][72] (cs reused as os)
  unsigned short* qs = sh;
  unsigned short* cs = sh + 64 * 72;
  unsigned short* os = cs;
  const int tid = threadIdx.x;

  for (int i = tid; i < 512; i += 256) {
    const int row = i >> 3, c8 = (i & 7) << 3;
    *(uint4*)&qs[row * 72 + c8] =
        *(const uint4*)&qb[(size_t)(t0 + row) * KDIM + h * 64 + c8];
  }
  for (int i = tid; i < 640; i += 256) {
    const int row = i >> 3, c8 = (i & 7) << 3;
    *(uint4*)&cs[row * 72 + c8] =
        *(const uint4*)&ctxb[(size_t)bh * 5120 + (row << 6) + c8];
  }
  __syncthreads();

  const int lane = tid & 63, w = tid >> 6, quad = lane >> 4, lr = lane & 15;
  floatx4 acc[5] = {};
#pragma unroll
  for (int k2 = 0; k2 < 2; k2++) {
    const int d0 = (k2 << 5) + (quad << 3);
    const frag8 bf = *(const frag8*)&qs[((w << 4) + lr) * 72 + d0];
#pragma unroll
    for (int et = 0; et < 5; et++) {
      const frag8 af = *(const frag8*)&cs[(et * 16 + lr) * 72 + d0];
      acc[et] = mfma16(af, bf, acc[et]);
    }
  }
  const float dinv = 1.f / __shfl(acc[4][0], lr);
  __syncthreads();                      // done reading cs; reuse as os

  const int trow = (w << 4) + lr;
#pragma unroll
  for (int et = 0; et < 4; et++)
#pragma unroll
    for (int r = 0; r < 4; r++) {
      const int e = et * 16 + (quad << 2) + r;
      const float qv = b2f(qs[trow * 72 + e]);
      os[trow * 72 + e] = f2b(acc[et][r] * dinv + qv);
    }
  __syncthreads();

  for (int i = tid; i < 512; i += 256) {
    const int row = i >> 3, c8 = (i & 7) << 3;
    *(uint4*)&opre[(size_t)(t0 + row) * KDIM + h * 64 + c8] = *(const uint4*)&os[row * 72 + c8];
  }
}

// ---------------- launch ----------------
extern "C" void kernel_launch(void* const* d_in, const int* in_sizes, int n_in,
                              void* d_out, int out_size, void* d_ws, size_t ws_size,
                              hipStream_t stream) {
  (void)in_sizes; (void)n_in; (void)out_size; (void)ws_size;
  const float* x  = (const float*)d_in[0];
  const float* Wq = (const float*)d_in[1];
  const float* bq = (const float*)d_in[2];
  const float* Wk = (const float*)d_in[3];
  const float* bk = (const float*)d_in[4];
  const float* Wv = (const float*)d_in[5];
  const float* bv = (const float*)d_in[6];
  const float* Wp = (const float*)d_in[7];
  const float* bp = (const float*)d_in[8];

  char* w = (char*)d_ws;
  unsigned short* xb   = (unsigned short*)w; w += (size_t)NTOK * KDIM * 2;   // 16 MB
  float* part          = (float*)xb;         // alias: xb dead after qkv GEMM
  unsigned short* wqkv = (unsigned short*)w; w += (size_t)NQKV * KDIM * 2;   // 1.5 MB
  unsigned short* wp   = (unsigned short*)w; w += (size_t)KDIM * KDIM * 2;   // 0.5 MB
  float* bias_qkv      = (float*)w;          w += (size_t)NQKV * 4;          // 6 KB
  float* ksp           = (float*)w;          w += (size_t)1024 * 64 * 4;     // 256 KB
  unsigned short* ctxb = (unsigned short*)w; w += (size_t)32 * 80 * 64 * 2;  // 320 KB
  unsigned short* qkv  = (unsigned short*)w; w += (size_t)NTOK * NQKV * 2;   // 48 MB
  unsigned short* opre = (unsigned short*)w; w += (size_t)NTOK * KDIM * 2;   // 16 MB

  unsigned short* qb  = qkv;                               // 16 MB [t][512]
  unsigned short* ktb = qkv + (size_t)NTOK * 512;          // 16 MB [bh][64][4096]
  unsigned short* vtb = ktb + (size_t)32 * 64 * TT;        // 16 MB [bh][64][4096]

  cvt_all<<<9222, 256, 0, stream>>>(x, Wq, Wk, Wv, Wp, bq, bk, bv,
                                    xb, wqkv, wp, bias_qkv);
  gemm_bt<1><<<(NTOK / 128) * (NQKV / 128), 256, 0, stream>>>(
      xb, wqkv, bias_qkv, qb, ktb, vtb, NTOK, NQKV, KDIM, 512);
  kv_context<<<512, 256, 0, stream>>>(ktb, vtb, part, ksp);
  ctx_reduce<<<160, 256, 0, stream>>>(part, ksp, ctxb);
  attn_out<<<2048, 256, 0, stream>>>(qb, ctxb, opre);
  gemm_bt<0><<<(NTOK / 128) * (KDIM / 128), 256, 0, stream>>>(
      opre, wp, bp, d_out, nullptr, nullptr, NTOK, KDIM, KDIM, KDIM);
}